// Round 5
// baseline (884.251 us; speedup 1.0000x reference)
//
#include <hip/hip_runtime.h>
#include <hip/hip_bf16.h>
#include <math.h>

#define N_TOK 8192
#define DIM   1024
#define HID   2048
#define NE    8

typedef __attribute__((ext_vector_type(8))) short short8;
typedef __attribute__((ext_vector_type(4))) float f32x4;

__device__ __forceinline__ unsigned short f2bf(float f) {
    unsigned int u = __builtin_bit_cast(unsigned int, f);
    unsigned int r = (u + 0x7fffu + ((u >> 16) & 1u)) >> 16;   // RNE
    return (unsigned short)r;
}

__device__ __forceinline__ short8 pack8(float4 a, float4 b) {
    short8 v;
    v[0] = (short)f2bf(a.x); v[1] = (short)f2bf(a.y);
    v[2] = (short)f2bf(a.z); v[3] = (short)f2bf(a.w);
    v[4] = (short)f2bf(b.x); v[5] = (short)f2bf(b.y);
    v[6] = (short)f2bf(b.z); v[7] = (short)f2bf(b.w);
    return v;
}

// async global -> LDS, 16 bytes per lane; lds dest is wave-uniform base (+ lane*16 by HW)
__device__ __forceinline__ void gl_lds16(const unsigned short* g, unsigned short* l) {
    __builtin_amdgcn_global_load_lds(
        (const __attribute__((address_space(1))) void*)g,
        (__attribute__((address_space(3))) void*)l, 16, 0, 0);
}

__device__ __forceinline__ void wait_vm0_barrier() {
    asm volatile("s_waitcnt vmcnt(0)" ::: "memory");
    __builtin_amdgcn_s_barrier();
}

// ---------------- gating: logits -> softmax -> top2 -> routing lists ----------------
__global__ __launch_bounds__(256) void gate_kernel(
    const float* __restrict__ x, const float* __restrict__ gw, const float* __restrict__ gb,
    float* __restrict__ usage, int* __restrict__ counts,
    int* __restrict__ lists, float* __restrict__ wts)
{
    const int wave_in_block = threadIdx.x >> 6;
    const int lane = threadIdx.x & 63;
    const int tok = blockIdx.x * 4 + wave_in_block;

    __shared__ float su[NE];
    if (threadIdx.x < NE) su[threadIdx.x] = 0.f;
    __syncthreads();

    float acc[NE];
#pragma unroll
    for (int e = 0; e < NE; e++) acc[e] = 0.f;

    const float* xr = x + (size_t)tok * DIM;
    for (int d = lane; d < DIM; d += 64) {
        float xv = xr[d];
        const float4* g4 = (const float4*)(gw + (size_t)d * NE);
        float4 ga = g4[0], gc = g4[1];
        acc[0] = fmaf(xv, ga.x, acc[0]);
        acc[1] = fmaf(xv, ga.y, acc[1]);
        acc[2] = fmaf(xv, ga.z, acc[2]);
        acc[3] = fmaf(xv, ga.w, acc[3]);
        acc[4] = fmaf(xv, gc.x, acc[4]);
        acc[5] = fmaf(xv, gc.y, acc[5]);
        acc[6] = fmaf(xv, gc.z, acc[6]);
        acc[7] = fmaf(xv, gc.w, acc[7]);
    }
#pragma unroll
    for (int e = 0; e < NE; e++) {
#pragma unroll
        for (int off = 32; off > 0; off >>= 1)
            acc[e] += __shfl_xor(acc[e], off);
    }

    if (lane == 0) {
        float lg[NE], p[NE];
        float mx = -1e30f;
#pragma unroll
        for (int e = 0; e < NE; e++) { lg[e] = acc[e] + gb[e]; mx = fmaxf(mx, lg[e]); }
        float s = 0.f;
#pragma unroll
        for (int e = 0; e < NE; e++) { p[e] = __expf(lg[e] - mx); s += p[e]; }
        float inv = 1.f / s;
#pragma unroll
        for (int e = 0; e < NE; e++) p[e] *= inv;

#pragma unroll
        for (int e = 0; e < NE; e++) atomicAdd(&su[e], p[e]);

        int e1 = 0; float v1 = p[0];
#pragma unroll
        for (int e = 1; e < NE; e++) if (p[e] > v1) { v1 = p[e]; e1 = e; }
        int e2 = -1; float v2 = -1e30f;
#pragma unroll
        for (int e = 0; e < NE; e++) if (e != e1 && p[e] > v2) { v2 = p[e]; e2 = e; }

        int pos1 = atomicAdd(&counts[e1], 1);
        lists[e1 * N_TOK + pos1] = tok * 2 + 0;
        wts[e1 * N_TOK + pos1] = v1;
        int pos2 = atomicAdd(&counts[e2], 1);
        lists[e2 * N_TOK + pos2] = tok * 2 + 1;
        wts[e2 * N_TOK + pos2] = v2;
    }
    __syncthreads();
    if (threadIdx.x < NE) atomicAdd(&usage[threadIdx.x], su[threadIdx.x]);
}

__global__ void loss_kernel(const float* __restrict__ usage, float* __restrict__ out_loss)
{
    if (threadIdx.x == 0) {
        float l = 0.f;
        for (int e = 0; e < NE; e++) {
            float u = usage[e] / (float)N_TOK;
            l += u * logf(u + 1e-9f);
        }
        *out_loss = l;
    }
}

// ---------------- x (f32) -> bf16, token-major ----------------
__global__ __launch_bounds__(256) void xconv_kernel(
    const float* __restrict__ x, unsigned short* __restrict__ xb)
{
    size_t i = ((size_t)blockIdx.x * 256 + threadIdx.x) * 8;
    float4 a = *(const float4*)(x + i);
    float4 b = *(const float4*)(x + i + 4);
    *(short8*)(xb + i) = pack8(a, b);
}

// ---------------- W (f32 [R][C]) -> WT (bf16 [C][R]) per expert ----------------
__global__ __launch_bounds__(256) void transpose_bf16_kernel(
    const float* __restrict__ in, unsigned short* __restrict__ out, int R, int C)
{
    __shared__ float Ls[64][65];
    const int e = blockIdx.z;
    const float* in_e = in + (size_t)e * R * C;
    unsigned short* out_e = out + (size_t)e * R * C;
    const int c0 = blockIdx.x * 64, r0 = blockIdx.y * 64;
    const int t = threadIdx.x;
    const int rr = t >> 4, cc = (t & 15) * 4;
#pragma unroll
    for (int it = 0; it < 4; it++) {
        float4 v = *(const float4*)(in_e + (size_t)(r0 + rr + it * 16) * C + c0 + cc);
        Ls[rr + it * 16][cc + 0] = v.x;
        Ls[rr + it * 16][cc + 1] = v.y;
        Ls[rr + it * 16][cc + 2] = v.z;
        Ls[rr + it * 16][cc + 3] = v.w;
    }
    __syncthreads();
#pragma unroll
    for (int it = 0; it < 2; it++) {
        int idx = t + it * 256;
        int a = idx >> 3, b8 = (idx & 7) * 8;
        short8 v;
#pragma unroll
        for (int j = 0; j < 8; j++) v[j] = (short)f2bf(Ls[b8 + j][a]);
        *(short8*)(out_e + (size_t)(c0 + a) * R + r0 + b8) = v;
    }
}

// ---------------- pass A: Xg @ {w1,w2} + bias -> swiglu -> Hbuf (bf16) ----------------
// 128x128xBK32 tile, 4 waves x (64x64, 4x4 frags), dual acc.
// 2-phase double-buffered K-loop: stage(t+1) -> compute(t) -> vmcnt(0)+barrier.
__global__ __launch_bounds__(256, 2) void ffn1_mfma_kernel(
    const unsigned short* __restrict__ Xbf,
    const unsigned short* __restrict__ W1T, const unsigned short* __restrict__ W2T,
    const float* __restrict__ b1, const float* __restrict__ b2,
    const int* __restrict__ counts, const int* __restrict__ lists,
    unsigned short* __restrict__ Hbuf)
{
    const int e = blockIdx.z;
    const int cnt = counts[e];
    const int m0 = blockIdx.y * 128;
    if (m0 >= cnt) return;
    const int n0 = blockIdx.x * 128;

    __shared__ __align__(16) unsigned short As[2][4096];   // 2 x 8 KB
    __shared__ __align__(16) unsigned short B1s[2][4096];
    __shared__ __align__(16) unsigned short B2s[2][4096];
    __shared__ int rowids[128];

    const int t = threadIdx.x;
    if (t < 128) {
        int idx = m0 + t;
        rowids[t] = (idx < cnt) ? lists[e * N_TOK + idx] : -1;
    }
    __syncthreads();

    const int srow = t & 127;
    const int kc_lo = t >> 7;                     // 0/1
    const int rid_s = rowids[srow];
    const unsigned short* Ap  = Xbf + (size_t)(rid_s < 0 ? 0 : (rid_s >> 1)) * DIM;
    const unsigned short* W1p = W1T + (size_t)e * DIM * HID + (size_t)(n0 + srow) * DIM;
    const unsigned short* W2p = W2T + (size_t)e * DIM * HID + (size_t)(n0 + srow) * DIM;
    const int lb0 = (t & ~63) * 8;                // LDS short-index base, issue 0
    const int lb1 = (256 + (t & ~63)) * 8;        // issue 1

    f32x4 acc1[4][4], acc2[4][4];
    const f32x4 fz = {0.f, 0.f, 0.f, 0.f};
#pragma unroll
    for (int i = 0; i < 4; i++)
#pragma unroll
        for (int j = 0; j < 4; j++) { acc1[i][j] = fz; acc2[i][j] = fz; }

    const int lane = t & 63, wv = t >> 6;
    const int wm = (wv >> 1) * 64, wn = (wv & 1) * 64;
    const int fr = lane & 15, kq = lane >> 4;

    // k-index helpers (shorts): chunk o0/o1 for a K-step base k0
    #define FFN1_STAGE(buf, k0) do {                          \
        const int o0 = (k0) + kc_lo * 8;                      \
        const int o1 = (k0) + (kc_lo + 2) * 8;                \
        gl_lds16(Ap + o0,  &As[buf][lb0]);                    \
        gl_lds16(Ap + o1,  &As[buf][lb1]);                    \
        gl_lds16(W1p + o0, &B1s[buf][lb0]);                   \
        gl_lds16(W1p + o1, &B1s[buf][lb1]);                   \
        gl_lds16(W2p + o0, &B2s[buf][lb0]);                   \
        gl_lds16(W2p + o1, &B2s[buf][lb1]);                   \
    } while (0)

    #define FFN1_COMPUTE(buf) do {                                                  \
        short8 af[4];                                                               \
        _Pragma("unroll")                                                           \
        for (int mi = 0; mi < 4; mi++)                                              \
            af[mi] = *(const short8*)&As[buf][(kq * 128 + wm + mi * 16 + fr) * 8];  \
        _Pragma("unroll")                                                           \
        for (int ni = 0; ni < 4; ni++) {                                            \
            short8 bf1 = *(const short8*)&B1s[buf][(kq * 128 + wn + ni * 16 + fr) * 8]; \
            short8 bf2 = *(const short8*)&B2s[buf][(kq * 128 + wn + ni * 16 + fr) * 8]; \
            _Pragma("unroll")                                                       \
            for (int mi = 0; mi < 4; mi++) {                                        \
                acc1[mi][ni] = __builtin_amdgcn_mfma_f32_16x16x32_bf16(af[mi], bf1, acc1[mi][ni], 0, 0, 0); \
                acc2[mi][ni] = __builtin_amdgcn_mfma_f32_16x16x32_bf16(af[mi], bf2, acc2[mi][ni], 0, 0, 0); \
            }                                                                       \
        }                                                                           \
    } while (0)

    FFN1_STAGE(0, 0);
    wait_vm0_barrier();
    for (int k0 = 0; k0 + 64 < DIM; k0 += 64) {
        FFN1_STAGE(1, k0 + 32);
        FFN1_COMPUTE(0);
        wait_vm0_barrier();
        FFN1_STAGE(0, k0 + 64);
        FFN1_COMPUTE(1);
        wait_vm0_barrier();
    }
    FFN1_STAGE(1, DIM - 32);
    FFN1_COMPUTE(0);
    wait_vm0_barrier();
    FFN1_COMPUTE(1);

    // epilogue: bias + swiglu, store bf16 H rows
#pragma unroll
    for (int ni = 0; ni < 4; ni++) {
        int col = n0 + wn + ni * 16 + fr;
        float bb1 = b1[e * HID + col];
        float bb2 = b2[e * HID + col];
#pragma unroll
        for (int mi = 0; mi < 4; mi++) {
#pragma unroll
            for (int j = 0; j < 4; j++) {
                int rl = wm + mi * 16 + kq * 4 + j;
                int rid = rowids[rl];
                if (rid < 0) continue;
                float v1 = acc1[mi][ni][j] + bb1;
                float v2 = acc2[mi][ni][j] + bb2;
                float h = v1 * (1.f / (1.f + __expf(-v2)));
                Hbuf[(size_t)rid * HID + col] = f2bf(h);
            }
        }
    }
}

// ---------------- pass B: Hg @ w3 + b3, scale, atomicAdd into out ----------------
__global__ __launch_bounds__(256, 2) void ffn2_mfma_kernel(
    const unsigned short* __restrict__ Hbuf,
    const unsigned short* __restrict__ W3T, const float* __restrict__ b3,
    const int* __restrict__ counts, const int* __restrict__ lists, const float* __restrict__ wts,
    float* __restrict__ out)
{
    const int e = blockIdx.z;
    const int cnt = counts[e];
    const int m0 = blockIdx.y * 128;
    if (m0 >= cnt) return;
    const int n0 = blockIdx.x * 128;

    __shared__ __align__(16) unsigned short As[2][4096];
    __shared__ __align__(16) unsigned short B3s[2][4096];
    __shared__ int rowids[128];
    __shared__ float rowwt[128];

    const int t = threadIdx.x;
    if (t < 128) {
        int idx = m0 + t;
        if (idx < cnt) { rowids[t] = lists[e * N_TOK + idx]; rowwt[t] = wts[e * N_TOK + idx]; }
        else           { rowids[t] = -1; rowwt[t] = 0.f; }
    }
    __syncthreads();

    const int srow = t & 127;
    const int kc_lo = t >> 7;
    const int rid_s = rowids[srow];
    const unsigned short* Ap  = Hbuf + (size_t)(rid_s < 0 ? 0 : rid_s) * HID;
    const unsigned short* W3p = W3T + (size_t)e * DIM * HID + (size_t)(n0 + srow) * HID;
    const int lb0 = (t & ~63) * 8;
    const int lb1 = (256 + (t & ~63)) * 8;

    f32x4 acc[4][4];
    const f32x4 fz = {0.f, 0.f, 0.f, 0.f};
#pragma unroll
    for (int i = 0; i < 4; i++)
#pragma unroll
        for (int j = 0; j < 4; j++) acc[i][j] = fz;

    const int lane = t & 63, wv = t >> 6;
    const int wm = (wv >> 1) * 64, wn = (wv & 1) * 64;
    const int fr = lane & 15, kq = lane >> 4;

    #define FFN2_STAGE(buf, k0) do {                          \
        const int o0 = (k0) + kc_lo * 8;                      \
        const int o1 = (k0) + (kc_lo + 2) * 8;                \
        gl_lds16(Ap + o0,  &As[buf][lb0]);                    \
        gl_lds16(Ap + o1,  &As[buf][lb1]);                    \
        gl_lds16(W3p + o0, &B3s[buf][lb0]);                   \
        gl_lds16(W3p + o1, &B3s[buf][lb1]);                   \
    } while (0)

    #define FFN2_COMPUTE(buf) do {                                                  \
        short8 af[4];                                                               \
        _Pragma("unroll")                                                           \
        for (int mi = 0; mi < 4; mi++)                                              \
            af[mi] = *(const short8*)&As[buf][(kq * 128 + wm + mi * 16 + fr) * 8];  \
        _Pragma("unroll")                                                           \
        for (int ni = 0; ni < 4; ni++) {                                            \
            short8 bf3 = *(const short8*)&B3s[buf][(kq * 128 + wn + ni * 16 + fr) * 8]; \
            _Pragma("unroll")                                                       \
            for (int mi = 0; mi < 4; mi++)                                          \
                acc[mi][ni] = __builtin_amdgcn_mfma_f32_16x16x32_bf16(af[mi], bf3, acc[mi][ni], 0, 0, 0); \
        }                                                                           \
    } while (0)

    FFN2_STAGE(0, 0);
    wait_vm0_barrier();
    for (int k0 = 0; k0 + 64 < HID; k0 += 64) {
        FFN2_STAGE(1, k0 + 32);
        FFN2_COMPUTE(0);
        wait_vm0_barrier();
        FFN2_STAGE(0, k0 + 64);
        FFN2_COMPUTE(1);
        wait_vm0_barrier();
    }
    FFN2_STAGE(1, HID - 32);
    FFN2_COMPUTE(0);
    wait_vm0_barrier();
    FFN2_COMPUTE(1);

#pragma unroll
    for (int ni = 0; ni < 4; ni++) {
        int col = n0 + wn + ni * 16 + fr;
        float bb3 = b3[e * DIM + col];
#pragma unroll
        for (int mi = 0; mi < 4; mi++) {
#pragma unroll
            for (int j = 0; j < 4; j++) {
                int rl = wm + mi * 16 + kq * 4 + j;
                int rid = rowids[rl];
                if (rid < 0) continue;
                float v = (acc[mi][ni][j] + bb3) * rowwt[rl];
                atomicAdd(&out[(size_t)(rid >> 1) * DIM + col], v);
            }
        }
    }
}

extern "C" void kernel_launch(void* const* d_in, const int* in_sizes, int n_in,
                              void* d_out, int out_size, void* d_ws, size_t ws_size,
                              hipStream_t stream) {
    (void)in_sizes; (void)n_in; (void)out_size; (void)ws_size;
    const float* x      = (const float*)d_in[0];
    const float* gate_w = (const float*)d_in[1];
    const float* gate_b = (const float*)d_in[2];
    const float* w1     = (const float*)d_in[3];
    const float* b1     = (const float*)d_in[4];
    const float* w2     = (const float*)d_in[5];
    const float* b2     = (const float*)d_in[6];
    const float* w3     = (const float*)d_in[7];
    const float* b3     = (const float*)d_in[8];
    float* out = (float*)d_out;

    char* ws = (char*)d_ws;
    float* usage  = (float*)ws;                                  // 32 B
    int*   counts = (int*)(ws + 32);                             // 32 B
    int*   lists  = (int*)(ws + 64);                             // 256 KB
    float* wts    = (float*)(ws + 64 + (size_t)NE * N_TOK * 4);  // 256 KB
    unsigned short* Hbuf = (unsigned short*)(ws + (1ull << 20));   // @1 MiB, 64 MiB
    unsigned short* W1T  = (unsigned short*)(ws + (65ull << 20));  // @65 MiB, 32 MiB
    unsigned short* W2T  = (unsigned short*)(ws + (97ull << 20));  // @97 MiB, 32 MiB
    unsigned short* W3T  = W1T;                                    // reused after ffn1
    unsigned short* Xbf  = (unsigned short*)d_out;                 // lives in d_out pre-zeroing

    hipMemsetAsync(ws, 0, 64, stream);

    gate_kernel<<<N_TOK / 4, 256, 0, stream>>>(x, gate_w, gate_b, usage, counts, lists, wts);
    xconv_kernel<<<N_TOK * DIM / (256 * 8), 256, 0, stream>>>(x, Xbf);

    dim3 gT1(HID / 64, DIM / 64, NE);
    transpose_bf16_kernel<<<gT1, 256, 0, stream>>>(w1, W1T, DIM, HID);
    transpose_bf16_kernel<<<gT1, 256, 0, stream>>>(w2, W2T, DIM, HID);

    dim3 gA(HID / 128, N_TOK / 128, NE);
    ffn1_mfma_kernel<<<gA, 256, 0, stream>>>(Xbf, W1T, W2T, b1, b2, counts, lists, Hbuf);

    hipMemsetAsync(d_out, 0, (size_t)N_TOK * DIM * sizeof(float), stream);
    loss_kernel<<<1, 64, 0, stream>>>(usage, out + (size_t)N_TOK * DIM);

    dim3 gT3(DIM / 64, HID / 64, NE);
    transpose_bf16_kernel<<<gT3, 256, 0, stream>>>(w3, W3T, HID, DIM);

    dim3 gB(DIM / 128, N_TOK / 128, NE);
    ffn2_mfma_kernel<<<gB, 256, 0, stream>>>(Hbuf, W3T, b3, counts, lists, wts, out);
}

// Round 6
// 708.503 us; speedup vs baseline: 1.2481x; 1.2481x over previous
//
#include <hip/hip_runtime.h>
#include <hip/hip_bf16.h>
#include <math.h>

#define N_TOK 8192
#define DIM   1024
#define HID   2048
#define NE    8
#define KS1   32     // DIM/32  k-steps (ffn1)
#define KS2   64     // HID/32  k-steps (ffn2)
#define NB1   16     // HID/128 n-blocks (ffn1)
#define NB2   8      // DIM/128 n-blocks (ffn2)

typedef __attribute__((ext_vector_type(8))) short short8;
typedef __attribute__((ext_vector_type(4))) float f32x4;

__device__ __forceinline__ unsigned short f2bf(float f) {
    unsigned int u = __builtin_bit_cast(unsigned int, f);
    unsigned int r = (u + 0x7fffu + ((u >> 16) & 1u)) >> 16;   // RNE
    return (unsigned short)r;
}

__device__ __forceinline__ short8 pack8(float4 a, float4 b) {
    short8 v;
    v[0] = (short)f2bf(a.x); v[1] = (short)f2bf(a.y);
    v[2] = (short)f2bf(a.z); v[3] = (short)f2bf(a.w);
    v[4] = (short)f2bf(b.x); v[5] = (short)f2bf(b.y);
    v[6] = (short)f2bf(b.z); v[7] = (short)f2bf(b.w);
    return v;
}

// async global -> LDS, 16B/lane; LDS dest = wave-uniform base + lane*16 (HW)
__device__ __forceinline__ void gl_lds16(const unsigned short* g, unsigned short* l) {
    __builtin_amdgcn_global_load_lds(
        (const __attribute__((address_space(1))) void*)g,
        (__attribute__((address_space(3))) void*)l, 16, 0, 0);
}

__device__ __forceinline__ void wait_vm0_barrier() {
    asm volatile("s_waitcnt vmcnt(0)" ::: "memory");
    __builtin_amdgcn_s_barrier();
}

// ---------------- gating ----------------
__global__ __launch_bounds__(256) void gate_kernel(
    const float* __restrict__ x, const float* __restrict__ gw, const float* __restrict__ gb,
    float* __restrict__ usage, int* __restrict__ counts,
    int* __restrict__ lists, float* __restrict__ wts)
{
    const int wave_in_block = threadIdx.x >> 6;
    const int lane = threadIdx.x & 63;
    const int tok = blockIdx.x * 4 + wave_in_block;

    __shared__ float su[NE];
    if (threadIdx.x < NE) su[threadIdx.x] = 0.f;
    __syncthreads();

    float acc[NE];
#pragma unroll
    for (int e = 0; e < NE; e++) acc[e] = 0.f;

    const float* xr = x + (size_t)tok * DIM;
    for (int d = lane; d < DIM; d += 64) {
        float xv = xr[d];
        const float4* g4 = (const float4*)(gw + (size_t)d * NE);
        float4 ga = g4[0], gc = g4[1];
        acc[0] = fmaf(xv, ga.x, acc[0]);
        acc[1] = fmaf(xv, ga.y, acc[1]);
        acc[2] = fmaf(xv, ga.z, acc[2]);
        acc[3] = fmaf(xv, ga.w, acc[3]);
        acc[4] = fmaf(xv, gc.x, acc[4]);
        acc[5] = fmaf(xv, gc.y, acc[5]);
        acc[6] = fmaf(xv, gc.z, acc[6]);
        acc[7] = fmaf(xv, gc.w, acc[7]);
    }
#pragma unroll
    for (int e = 0; e < NE; e++) {
#pragma unroll
        for (int off = 32; off > 0; off >>= 1)
            acc[e] += __shfl_xor(acc[e], off);
    }

    if (lane == 0) {
        float lg[NE], p[NE];
        float mx = -1e30f;
#pragma unroll
        for (int e = 0; e < NE; e++) { lg[e] = acc[e] + gb[e]; mx = fmaxf(mx, lg[e]); }
        float s = 0.f;
#pragma unroll
        for (int e = 0; e < NE; e++) { p[e] = __expf(lg[e] - mx); s += p[e]; }
        float inv = 1.f / s;
#pragma unroll
        for (int e = 0; e < NE; e++) p[e] *= inv;

#pragma unroll
        for (int e = 0; e < NE; e++) atomicAdd(&su[e], p[e]);

        int e1 = 0; float v1 = p[0];
#pragma unroll
        for (int e = 1; e < NE; e++) if (p[e] > v1) { v1 = p[e]; e1 = e; }
        int e2 = -1; float v2 = -1e30f;
#pragma unroll
        for (int e = 0; e < NE; e++) if (e != e1 && p[e] > v2) { v2 = p[e]; e2 = e; }

        int pos1 = atomicAdd(&counts[e1], 1);
        lists[e1 * N_TOK + pos1] = tok * 2 + 0;
        wts[e1 * N_TOK + pos1] = v1;
        int pos2 = atomicAdd(&counts[e2], 1);
        lists[e2 * N_TOK + pos2] = tok * 2 + 1;
        wts[e2 * N_TOK + pos2] = v2;
    }
    __syncthreads();
    if (threadIdx.x < NE) atomicAdd(&usage[threadIdx.x], su[threadIdx.x]);
}

__global__ void loss_kernel(const float* __restrict__ usage, float* __restrict__ out_loss)
{
    if (threadIdx.x == 0) {
        float l = 0.f;
        for (int e = 0; e < NE; e++) {
            float u = usage[e] / (float)N_TOK;
            l += u * logf(u + 1e-9f);
        }
        *out_loss = l;
    }
}

// base[e] = 128-aligned prefix of counts
__global__ void prefix_kernel(const int* __restrict__ counts, int* __restrict__ base)
{
    if (threadIdx.x == 0) {
        int b = 0;
        for (int e = 0; e < NE; e++) { base[e] = b; b += (counts[e] + 127) & ~127; }
    }
}

// ---------------- x (f32) -> bf16, token-major ----------------
__global__ __launch_bounds__(256) void xconv_kernel(
    const float* __restrict__ x, unsigned short* __restrict__ xb)
{
    size_t i = ((size_t)blockIdx.x * 256 + threadIdx.x) * 8;
    float4 a = *(const float4*)(x + i);
    float4 b = *(const float4*)(x + i + 4);
    *(short8*)(xb + i) = pack8(a, b);
}

// ---------------- W (f32 [K][N]) -> swizzled bf16 tiles [e][nb][ks][kq][row][8] ----------------
// One block per (ks, nb, e); element (n = nb*128+row, k = ks*32+kq*8+s).
__global__ __launch_bounds__(256) void wswz_kernel(
    const float* __restrict__ in, unsigned short* __restrict__ out, int K, int N)
{
    const int e  = blockIdx.z;
    const int nb = blockIdx.y;
    const int ks = blockIdx.x;
    const int KSN = K >> 5;
    const float* in_e = in + (size_t)e * K * N;
    unsigned short* out_t = out + ((size_t)e * (N >> 7) * KSN + (size_t)nb * KSN + ks) * 4096;
    const int t = threadIdx.x;
#pragma unroll
    for (int it = 0; it < 2; it++) {
        int idx = it * 256 + t;          // chunk index 0..511
        int row = idx & 127;
        int kq  = idx >> 7;
        int kb  = ks * 32 + kq * 8;
        const float* src = in_e + (size_t)kb * N + nb * 128 + row;
        short8 v;
#pragma unroll
        for (int s = 0; s < 8; s++) v[s] = (short)f2bf(src[(size_t)s * N]);
        *(short8*)(out_t + (size_t)idx * 8) = v;
    }
}

// ---------------- pass A: Xg @ {w1,w2} -> swiglu -> Hsw (bf16, list-order, tiled) ----------------
__global__ __launch_bounds__(256, 2) void ffn1_mfma_kernel(
    const unsigned short* __restrict__ Xbf,
    const unsigned short* __restrict__ W1sw, const unsigned short* __restrict__ W2sw,
    const float* __restrict__ b1, const float* __restrict__ b2,
    const int* __restrict__ counts, const int* __restrict__ lists, const int* __restrict__ base,
    unsigned short* __restrict__ Hsw)
{
    const int e = blockIdx.z;
    const int cnt = counts[e];
    const int m0 = blockIdx.y * 128;
    if (m0 >= cnt) return;
    const int n0 = blockIdx.x * 128;
    const int nb = blockIdx.x;

    __shared__ __align__(16) unsigned short As[2][4096];
    __shared__ __align__(16) unsigned short B1s[2][4096];
    __shared__ __align__(16) unsigned short B2s[2][4096];
    __shared__ int rowids[128];

    const int t = threadIdx.x;
    if (t < 128) {
        int idx = m0 + t;
        rowids[t] = (idx < cnt) ? lists[e * N_TOK + idx] : -1;
    }
    __syncthreads();

    // A staging (gathered token rows): thread t -> row t&127, k-chunks kc_lo & kc_lo+2
    const int srow = t & 127;
    const int kc_lo = t >> 7;
    const int rid_s = rowids[srow];
    const unsigned short* Ap = Xbf + (size_t)(rid_s < 0 ? 0 : (rid_s >> 1)) * DIM;
    // B staging (pre-swizzled, fully coalesced): tile base per (e, nb)
    const unsigned short* W1t = W1sw + ((size_t)e * NB1 + nb) * (KS1 * 4096);
    const unsigned short* W2t = W2sw + ((size_t)e * NB1 + nb) * (KS1 * 4096);
    const int lb0 = (t & ~63) * 8;            // LDS short-index base, chunks 0..255
    const int lb1 = (256 + (t & ~63)) * 8;    // chunks 256..511

    f32x4 acc1[4][4], acc2[4][4];
    const f32x4 fz = {0.f, 0.f, 0.f, 0.f};
#pragma unroll
    for (int i = 0; i < 4; i++)
#pragma unroll
        for (int j = 0; j < 4; j++) { acc1[i][j] = fz; acc2[i][j] = fz; }

    const int lane = t & 63, wv = t >> 6;
    const int wm = (wv >> 1) * 64, wn = (wv & 1) * 64;
    const int fr = lane & 15, kq = lane >> 4;

    #define FFN1_STAGE(buf, ks) do {                              \
        const int o0 = (ks) * 32 + kc_lo * 8;                     \
        const int o1 = (ks) * 32 + (kc_lo + 2) * 8;               \
        const unsigned short* w1tile = W1t + (ks) * 4096;         \
        const unsigned short* w2tile = W2t + (ks) * 4096;         \
        gl_lds16(w1tile + t * 8,        &B1s[buf][lb0]);          \
        gl_lds16(w1tile + 2048 + t * 8, &B1s[buf][lb1]);          \
        gl_lds16(w2tile + t * 8,        &B2s[buf][lb0]);          \
        gl_lds16(w2tile + 2048 + t * 8, &B2s[buf][lb1]);          \
        gl_lds16(Ap + o0,               &As[buf][lb0]);           \
        gl_lds16(Ap + o1,               &As[buf][lb1]);           \
    } while (0)

    #define FFN1_COMPUTE(buf) do {                                                  \
        short8 af[4];                                                               \
        _Pragma("unroll")                                                           \
        for (int mi = 0; mi < 4; mi++)                                              \
            af[mi] = *(const short8*)&As[buf][(kq * 128 + wm + mi * 16 + fr) * 8];  \
        _Pragma("unroll")                                                           \
        for (int ni = 0; ni < 4; ni++) {                                            \
            short8 bf1 = *(const short8*)&B1s[buf][(kq * 128 + wn + ni * 16 + fr) * 8]; \
            short8 bf2 = *(const short8*)&B2s[buf][(kq * 128 + wn + ni * 16 + fr) * 8]; \
            _Pragma("unroll")                                                       \
            for (int mi = 0; mi < 4; mi++) {                                        \
                acc1[mi][ni] = __builtin_amdgcn_mfma_f32_16x16x32_bf16(af[mi], bf1, acc1[mi][ni], 0, 0, 0); \
                acc2[mi][ni] = __builtin_amdgcn_mfma_f32_16x16x32_bf16(af[mi], bf2, acc2[mi][ni], 0, 0, 0); \
            }                                                                       \
        }                                                                           \
    } while (0)

    FFN1_STAGE(0, 0);
    wait_vm0_barrier();
    for (int ks = 0; ks + 2 < KS1; ks += 2) {
        FFN1_STAGE(1, ks + 1);
        FFN1_COMPUTE(0);
        wait_vm0_barrier();
        FFN1_STAGE(0, ks + 2);
        FFN1_COMPUTE(1);
        wait_vm0_barrier();
    }
    FFN1_STAGE(1, KS1 - 1);
    FFN1_COMPUTE(0);
    wait_vm0_barrier();
    FFN1_COMPUTE(1);

    // epilogue: bias + swiglu -> Hsw (list-order rows, k-tiled layout for ffn2 DMA)
    const int hb = base[e] + m0;                         // 128-aligned
    unsigned short* Hblk = Hsw + (size_t)(hb >> 7) * (KS2 * 4096);
#pragma unroll
    for (int ni = 0; ni < 4; ni++) {
        int col = n0 + wn + ni * 16 + fr;
        float bb1 = b1[e * HID + col];
        float bb2 = b2[e * HID + col];
        int coff = ((col >> 5) * 4 + ((col & 31) >> 3)) * 1024 + (col & 7);
#pragma unroll
        for (int mi = 0; mi < 4; mi++) {
#pragma unroll
            for (int j = 0; j < 4; j++) {
                int rl = wm + mi * 16 + kq * 4 + j;
                if (rowids[rl] < 0) continue;
                float v1 = acc1[mi][ni][j] + bb1;
                float v2 = acc2[mi][ni][j] + bb2;
                float h = v1 * (1.f / (1.f + __expf(-v2)));
                Hblk[coff + rl * 8] = f2bf(h);
            }
        }
    }
}

// ---------------- pass B: Hsw @ w3 + b3, scale, atomicAdd into out ----------------
__global__ __launch_bounds__(256, 2) void ffn2_mfma_kernel(
    const unsigned short* __restrict__ Hsw,
    const unsigned short* __restrict__ W3sw, const float* __restrict__ b3,
    const int* __restrict__ counts, const int* __restrict__ lists, const float* __restrict__ wts,
    const int* __restrict__ base,
    float* __restrict__ out)
{
    const int e = blockIdx.z;
    const int cnt = counts[e];
    const int m0 = blockIdx.y * 128;
    if (m0 >= cnt) return;
    const int n0 = blockIdx.x * 128;
    const int nb = blockIdx.x;

    __shared__ __align__(16) unsigned short As[2][4096];
    __shared__ __align__(16) unsigned short B3s[2][4096];
    __shared__ int rowids[128];
    __shared__ float rowwt[128];

    const int t = threadIdx.x;
    if (t < 128) {
        int idx = m0 + t;
        if (idx < cnt) { rowids[t] = lists[e * N_TOK + idx]; rowwt[t] = wts[e * N_TOK + idx]; }
        else           { rowids[t] = -1; rowwt[t] = 0.f; }
    }
    __syncthreads();

    const int hb = base[e] + m0;
    const unsigned short* Ht  = Hsw + (size_t)(hb >> 7) * (KS2 * 4096);
    const unsigned short* W3t = W3sw + ((size_t)e * NB2 + nb) * (KS2 * 4096);
    const int lb0 = (t & ~63) * 8;
    const int lb1 = (256 + (t & ~63)) * 8;

    f32x4 acc[4][4];
    const f32x4 fz = {0.f, 0.f, 0.f, 0.f};
#pragma unroll
    for (int i = 0; i < 4; i++)
#pragma unroll
        for (int j = 0; j < 4; j++) acc[i][j] = fz;

    const int lane = t & 63, wv = t >> 6;
    const int wm = (wv >> 1) * 64, wn = (wv & 1) * 64;
    const int fr = lane & 15, kq = lane >> 4;

    #define FFN2_STAGE(buf, ks) do {                              \
        const unsigned short* htile = Ht + (ks) * 4096;           \
        const unsigned short* wtile = W3t + (ks) * 4096;          \
        gl_lds16(htile + t * 8,        &As[buf][lb0]);            \
        gl_lds16(htile + 2048 + t * 8, &As[buf][lb1]);            \
        gl_lds16(wtile + t * 8,        &B3s[buf][lb0]);           \
        gl_lds16(wtile + 2048 + t * 8, &B3s[buf][lb1]);           \
    } while (0)

    #define FFN2_COMPUTE(buf) do {                                                  \
        short8 af[4];                                                               \
        _Pragma("unroll")                                                           \
        for (int mi = 0; mi < 4; mi++)                                              \
            af[mi] = *(const short8*)&As[buf][(kq * 128 + wm + mi * 16 + fr) * 8];  \
        _Pragma("unroll")                                                           \
        for (int ni = 0; ni < 4; ni++) {                                            \
            short8 bf3 = *(const short8*)&B3s[buf][(kq * 128 + wn + ni * 16 + fr) * 8]; \
            _Pragma("unroll")                                                       \
            for (int mi = 0; mi < 4; mi++)                                          \
                acc[mi][ni] = __builtin_amdgcn_mfma_f32_16x16x32_bf16(af[mi], bf3, acc[mi][ni], 0, 0, 0); \
        }                                                                           \
    } while (0)

    FFN2_STAGE(0, 0);
    wait_vm0_barrier();
    for (int ks = 0; ks + 2 < KS2; ks += 2) {
        FFN2_STAGE(1, ks + 1);
        FFN2_COMPUTE(0);
        wait_vm0_barrier();
        FFN2_STAGE(0, ks + 2);
        FFN2_COMPUTE(1);
        wait_vm0_barrier();
    }
    FFN2_STAGE(1, KS2 - 1);
    FFN2_COMPUTE(0);
    wait_vm0_barrier();
    FFN2_COMPUTE(1);

#pragma unroll
    for (int ni = 0; ni < 4; ni++) {
        int col = n0 + wn + ni * 16 + fr;
        float bb3 = b3[e * DIM + col];
#pragma unroll
        for (int mi = 0; mi < 4; mi++) {
#pragma unroll
            for (int j = 0; j < 4; j++) {
                int rl = wm + mi * 16 + kq * 4 + j;
                int rid = rowids[rl];
                if (rid < 0) continue;
                float v = (acc[mi][ni][j] + bb3) * rowwt[rl];
                atomicAdd(&out[(size_t)(rid >> 1) * DIM + col], v);
            }
        }
    }
}

extern "C" void kernel_launch(void* const* d_in, const int* in_sizes, int n_in,
                              void* d_out, int out_size, void* d_ws, size_t ws_size,
                              hipStream_t stream) {
    (void)in_sizes; (void)n_in; (void)out_size; (void)ws_size;
    const float* x      = (const float*)d_in[0];
    const float* gate_w = (const float*)d_in[1];
    const float* gate_b = (const float*)d_in[2];
    const float* w1     = (const float*)d_in[3];
    const float* b1     = (const float*)d_in[4];
    const float* w2     = (const float*)d_in[5];
    const float* b2     = (const float*)d_in[6];
    const float* w3     = (const float*)d_in[7];
    const float* b3     = (const float*)d_in[8];
    float* out = (float*)d_out;

    char* ws = (char*)d_ws;
    float* usage  = (float*)ws;                                   // @0, 32 B
    int*   counts = (int*)(ws + 32);                              // @32, 32 B
    int*   base   = (int*)(ws + 64);                              // @64, 64 B
    int*   lists  = (int*)(ws + 128);                             // 256 KB
    float* wts    = (float*)(ws + 128 + (size_t)NE * N_TOK * 4);  // 256 KB
    unsigned short* Hsw  = (unsigned short*)(ws + (1ull  << 20)); // @1 MiB, 68 MiB (17408 rows max)
    unsigned short* W1sw = (unsigned short*)(ws + (70ull << 20)); // @70 MiB, 32 MiB
    unsigned short* W2sw = (unsigned short*)(ws + (102ull << 20));// @102 MiB, 32 MiB
    unsigned short* W3sw = W1sw;                                  // reused after ffn1
    unsigned short* Xbf  = (unsigned short*)d_out;                // lives in d_out pre-zeroing

    hipMemsetAsync(ws, 0, 128, stream);

    gate_kernel<<<N_TOK / 4, 256, 0, stream>>>(x, gate_w, gate_b, usage, counts, lists, wts);
    prefix_kernel<<<1, 64, 0, stream>>>(counts, base);
    xconv_kernel<<<N_TOK * DIM / (256 * 8), 256, 0, stream>>>(x, Xbf);

    dim3 gW1(KS1, NB1, NE);                 // w1,w2: K=DIM, N=HID
    wswz_kernel<<<gW1, 256, 0, stream>>>(w1, W1sw, DIM, HID);
    wswz_kernel<<<gW1, 256, 0, stream>>>(w2, W2sw, DIM, HID);

    dim3 gA(NB1, N_TOK / 128, NE);
    ffn1_mfma_kernel<<<gA, 256, 0, stream>>>(Xbf, W1sw, W2sw, b1, b2, counts, lists, base, Hsw);

    hipMemsetAsync(d_out, 0, (size_t)N_TOK * DIM * sizeof(float), stream);
    loss_kernel<<<1, 64, 0, stream>>>(usage, out + (size_t)N_TOK * DIM);

    dim3 gW3(KS2, NB2, NE);                 // w3: K=HID, N=DIM
    wswz_kernel<<<gW3, 256, 0, stream>>>(w3, W3sw, HID, DIM);

    dim3 gB(NB2, N_TOK / 128, NE);
    ffn2_mfma_kernel<<<gB, 256, 0, stream>>>(Hsw, W3sw, b3, counts, lists, wts, base, out);
}

// Round 7
// 703.601 us; speedup vs baseline: 1.2567x; 1.0070x over previous
//
#include <hip/hip_runtime.h>
#include <hip/hip_bf16.h>
#include <math.h>

#define N_TOK 8192
#define DIM   1024
#define HID   2048
#define NE    8
#define KS1   32     // DIM/32  k-steps (ffn1)
#define KS2   64     // HID/32  k-steps (ffn2)
#define NB1   16     // HID/128 n-panels (ffn1)
#define NB2   8      // DIM/128 n-panels (ffn2)

typedef __attribute__((ext_vector_type(8))) short short8;
typedef __attribute__((ext_vector_type(4))) float f32x4;

__device__ __forceinline__ unsigned short f2bf(float f) {
    unsigned int u = __builtin_bit_cast(unsigned int, f);
    unsigned int r = (u + 0x7fffu + ((u >> 16) & 1u)) >> 16;   // RNE
    return (unsigned short)r;
}

__device__ __forceinline__ short8 pack8(float4 a, float4 b) {
    short8 v;
    v[0] = (short)f2bf(a.x); v[1] = (short)f2bf(a.y);
    v[2] = (short)f2bf(a.z); v[3] = (short)f2bf(a.w);
    v[4] = (short)f2bf(b.x); v[5] = (short)f2bf(b.y);
    v[6] = (short)f2bf(b.z); v[7] = (short)f2bf(b.w);
    return v;
}

// async global -> LDS, 16B/lane; LDS dest = wave-uniform base + lane*16 (HW)
__device__ __forceinline__ void gl_lds16(const unsigned short* g, unsigned short* l) {
    __builtin_amdgcn_global_load_lds(
        (const __attribute__((address_space(1))) void*)g,
        (__attribute__((address_space(3))) void*)l, 16, 0, 0);
}

// ---------------- gating ----------------
__global__ __launch_bounds__(256) void gate_kernel(
    const float* __restrict__ x, const float* __restrict__ gw, const float* __restrict__ gb,
    float* __restrict__ usage, int* __restrict__ counts,
    int* __restrict__ lists, float* __restrict__ wts)
{
    const int wave_in_block = threadIdx.x >> 6;
    const int lane = threadIdx.x & 63;
    const int tok = blockIdx.x * 4 + wave_in_block;

    __shared__ float su[NE];
    if (threadIdx.x < NE) su[threadIdx.x] = 0.f;
    __syncthreads();

    float acc[NE];
#pragma unroll
    for (int e = 0; e < NE; e++) acc[e] = 0.f;

    const float* xr = x + (size_t)tok * DIM;
    for (int d = lane; d < DIM; d += 64) {
        float xv = xr[d];
        const float4* g4 = (const float4*)(gw + (size_t)d * NE);
        float4 ga = g4[0], gc = g4[1];
        acc[0] = fmaf(xv, ga.x, acc[0]);
        acc[1] = fmaf(xv, ga.y, acc[1]);
        acc[2] = fmaf(xv, ga.z, acc[2]);
        acc[3] = fmaf(xv, ga.w, acc[3]);
        acc[4] = fmaf(xv, gc.x, acc[4]);
        acc[5] = fmaf(xv, gc.y, acc[5]);
        acc[6] = fmaf(xv, gc.z, acc[6]);
        acc[7] = fmaf(xv, gc.w, acc[7]);
    }
#pragma unroll
    for (int e = 0; e < NE; e++) {
#pragma unroll
        for (int off = 32; off > 0; off >>= 1)
            acc[e] += __shfl_xor(acc[e], off);
    }

    if (lane == 0) {
        float lg[NE], p[NE];
        float mx = -1e30f;
#pragma unroll
        for (int e = 0; e < NE; e++) { lg[e] = acc[e] + gb[e]; mx = fmaxf(mx, lg[e]); }
        float s = 0.f;
#pragma unroll
        for (int e = 0; e < NE; e++) { p[e] = __expf(lg[e] - mx); s += p[e]; }
        float inv = 1.f / s;
#pragma unroll
        for (int e = 0; e < NE; e++) p[e] *= inv;

#pragma unroll
        for (int e = 0; e < NE; e++) atomicAdd(&su[e], p[e]);

        int e1 = 0; float v1 = p[0];
#pragma unroll
        for (int e = 1; e < NE; e++) if (p[e] > v1) { v1 = p[e]; e1 = e; }
        int e2 = -1; float v2 = -1e30f;
#pragma unroll
        for (int e = 0; e < NE; e++) if (e != e1 && p[e] > v2) { v2 = p[e]; e2 = e; }

        int pos1 = atomicAdd(&counts[e1], 1);
        lists[e1 * N_TOK + pos1] = tok * 2 + 0;
        wts[e1 * N_TOK + pos1] = v1;
        int pos2 = atomicAdd(&counts[e2], 1);
        lists[e2 * N_TOK + pos2] = tok * 2 + 1;
        wts[e2 * N_TOK + pos2] = v2;
    }
    __syncthreads();
    if (threadIdx.x < NE) atomicAdd(&usage[threadIdx.x], su[threadIdx.x]);
}

__global__ void loss_kernel(const float* __restrict__ usage, float* __restrict__ out_loss)
{
    if (threadIdx.x == 0) {
        float l = 0.f;
        for (int e = 0; e < NE; e++) {
            float u = usage[e] / (float)N_TOK;
            l += u * logf(u + 1e-9f);
        }
        *out_loss = l;
    }
}

// base[e] = 128-aligned prefix of counts
__global__ void prefix_kernel(const int* __restrict__ counts, int* __restrict__ base)
{
    if (threadIdx.x == 0) {
        int b = 0;
        for (int e = 0; e < NE; e++) { base[e] = b; b += (counts[e] + 127) & ~127; }
    }
}

// ---------------- x (f32) -> bf16, token-major ----------------
__global__ __launch_bounds__(256) void xconv_kernel(
    const float* __restrict__ x, unsigned short* __restrict__ xb)
{
    size_t i = ((size_t)blockIdx.x * 256 + threadIdx.x) * 8;
    float4 a = *(const float4*)(x + i);
    float4 b = *(const float4*)(x + i + 4);
    *(short8*)(xb + i) = pack8(a, b);
}

// ---------------- W (f32 [K][N]) -> swizzled bf16 tiles [e][nb][ks][kq][row][8] ----------------
__global__ __launch_bounds__(256) void wswz_kernel(
    const float* __restrict__ in, unsigned short* __restrict__ out, int K, int N)
{
    const int e  = blockIdx.z;
    const int nb = blockIdx.y;
    const int ks = blockIdx.x;
    const int KSN = K >> 5;
    const float* in_e = in + (size_t)e * K * N;
    unsigned short* out_t = out + ((size_t)e * (N >> 7) * KSN + (size_t)nb * KSN + ks) * 4096;
    const int t = threadIdx.x;
#pragma unroll
    for (int it = 0; it < 2; it++) {
        int idx = it * 256 + t;          // chunk index 0..511
        int row = idx & 127;
        int kq  = idx >> 7;
        int kb  = ks * 32 + kq * 8;
        const float* src = in_e + (size_t)kb * N + nb * 128 + row;
        short8 v;
#pragma unroll
        for (int s = 0; s < 8; s++) v[s] = (short)f2bf(src[(size_t)s * N]);
        *(short8*)(out_t + (size_t)idx * 8) = v;
    }
}

// ---------------- pass A: Xg @ {w1,w2} -> swiglu -> Hsw ----------------
// BM=256, dual BN=128, BK=32, 8 waves; counted-vmcnt double-buffered pipeline.
__global__ __launch_bounds__(512, 2) void ffn1_mfma_kernel(
    const unsigned short* __restrict__ Xbf,
    const unsigned short* __restrict__ W1sw, const unsigned short* __restrict__ W2sw,
    const float* __restrict__ b1, const float* __restrict__ b2,
    const int* __restrict__ counts, const int* __restrict__ lists, const int* __restrict__ base,
    unsigned short* __restrict__ Hsw)
{
    const int e = blockIdx.z;
    const int cnt = counts[e];
    const int m0 = blockIdx.y * 256;
    if (m0 >= cnt) return;
    const int nb = blockIdx.x;
    const int n0 = nb * 128;

    __shared__ __align__(16) unsigned short As[2][8192];   // 2 x 16 KB
    __shared__ __align__(16) unsigned short B1s[2][4096];  // 2 x 8 KB
    __shared__ __align__(16) unsigned short B2s[2][4096];
    __shared__ int rowids[256];

    const int t = threadIdx.x;
    if (t < 256) {
        int idx = m0 + t;
        rowids[t] = (idx < cnt) ? lists[e * N_TOK + idx] : -1;
    }

    const int lane = t & 63, wv = t >> 6;
    const int wm = (wv >> 1) * 64, wn = (wv & 1) * 64;
    const int fr = lane & 15, kq = lane >> 4;

    // bias preload BEFORE the sync so no VMEM is outstanding inside the K-loop
    float bb1[4], bb2[4];
#pragma unroll
    for (int ni = 0; ni < 4; ni++) {
        int col = n0 + wn + ni * 16 + fr;
        bb1[ni] = b1[e * HID + col];
        bb2[ni] = b2[e * HID + col];
    }
    __syncthreads();   // rowids visible + all prior VMEM drained (vmcnt=0)

    const int srow = t & 255;       // A staging row
    const int kqA  = t >> 8;        // 0/1
    const int rid_s = rowids[srow];
    const unsigned short* Ap  = Xbf + (size_t)(rid_s < 0 ? 0 : (rid_s >> 1)) * DIM;
    const unsigned short* W1t = W1sw + ((size_t)e * NB1 + nb) * (KS1 * 4096);
    const unsigned short* W2t = W2sw + ((size_t)e * NB1 + nb) * (KS1 * 4096);
    const int lbA0 = (t & ~63) * 8;            // A chunks 0..511
    const int lbA1 = (512 + (t & ~63)) * 8;    // A chunks 512..1023
    const int lbB  = (t & ~63) * 8;

    f32x4 acc1[4][4], acc2[4][4];
    const f32x4 fz = {0.f, 0.f, 0.f, 0.f};
#pragma unroll
    for (int i = 0; i < 4; i++)
#pragma unroll
        for (int j = 0; j < 4; j++) { acc1[i][j] = fz; acc2[i][j] = fz; }

    #define F1_STAGE(buf, ks) do {                                   \
        const int o0 = (ks) * 32 + kqA * 8;                          \
        const int o1 = (ks) * 32 + (kqA + 2) * 8;                    \
        gl_lds16(Ap + o0, &As[buf][lbA0]);                           \
        gl_lds16(Ap + o1, &As[buf][lbA1]);                           \
        gl_lds16(W1t + (ks) * 4096 + t * 8, &B1s[buf][lbB]);         \
        gl_lds16(W2t + (ks) * 4096 + t * 8, &B2s[buf][lbB]);         \
    } while (0)

    #define F1_COMPUTE(buf) do {                                                    \
        short8 af[4];                                                               \
        _Pragma("unroll")                                                           \
        for (int mi = 0; mi < 4; mi++)                                              \
            af[mi] = *(const short8*)&As[buf][(kq * 256 + wm + mi * 16 + fr) * 8];  \
        _Pragma("unroll")                                                           \
        for (int ni = 0; ni < 4; ni++) {                                            \
            short8 bf1 = *(const short8*)&B1s[buf][(kq * 128 + wn + ni * 16 + fr) * 8]; \
            short8 bf2 = *(const short8*)&B2s[buf][(kq * 128 + wn + ni * 16 + fr) * 8]; \
            _Pragma("unroll")                                                       \
            for (int mi = 0; mi < 4; mi++) {                                        \
                acc1[mi][ni] = __builtin_amdgcn_mfma_f32_16x16x32_bf16(af[mi], bf1, acc1[mi][ni], 0, 0, 0); \
                acc2[mi][ni] = __builtin_amdgcn_mfma_f32_16x16x32_bf16(af[mi], bf2, acc2[mi][ni], 0, 0, 0); \
            }                                                                       \
        }                                                                           \
    } while (0)

    #define VM4  asm volatile("s_waitcnt vmcnt(4)" ::: "memory")
    #define VM0  asm volatile("s_waitcnt vmcnt(0)" ::: "memory")
    #define BAR  __builtin_amdgcn_s_barrier()

    F1_STAGE(0, 0);
    for (int ks = 0; ks < KS1 - 2; ks += 2) {
        F1_STAGE(1, ks + 1); VM4; BAR; F1_COMPUTE(0); BAR;
        F1_STAGE(0, ks + 2); VM4; BAR; F1_COMPUTE(1); BAR;
    }
    F1_STAGE(1, KS1 - 1); VM4; BAR; F1_COMPUTE(0); BAR;
    VM0; BAR; F1_COMPUTE(1);

    // epilogue: bias + swiglu -> Hsw (128-row tiled layout for ffn2 DMA)
    const int hb7 = (base[e] + m0) >> 7;
#pragma unroll
    for (int ni = 0; ni < 4; ni++) {
        int col = n0 + wn + ni * 16 + fr;
        int coff = (col >> 5) * 4096 + (((col & 31) >> 3)) * 1024 + (col & 7);
#pragma unroll
        for (int mi = 0; mi < 4; mi++) {
#pragma unroll
            for (int j = 0; j < 4; j++) {
                int rl = wm + mi * 16 + kq * 4 + j;
                if (rowids[rl] < 0) continue;
                float v1 = acc1[mi][ni][j] + bb1[ni];
                float v2 = acc2[mi][ni][j] + bb2[ni];
                float h = v1 * (1.f / (1.f + __expf(-v2)));
                Hsw[(size_t)(hb7 + (rl >> 7)) * (KS2 * 4096) + coff + (rl & 127) * 8] = f2bf(h);
            }
        }
    }
    #undef F1_STAGE
    #undef F1_COMPUTE
}

// ---------------- pass B: Hsw @ w3 + b3, scale, atomicAdd into out ----------------
// BM=256, BN=128, BK=32, 8 waves; counted-vmcnt pipeline.
__global__ __launch_bounds__(512, 2) void ffn2_mfma_kernel(
    const unsigned short* __restrict__ Hsw,
    const unsigned short* __restrict__ W3sw, const float* __restrict__ b3,
    const int* __restrict__ counts, const int* __restrict__ lists, const float* __restrict__ wts,
    const int* __restrict__ base,
    float* __restrict__ out)
{
    const int e = blockIdx.z;
    const int cnt = counts[e];
    const int m0 = blockIdx.y * 256;
    if (m0 >= cnt) return;
    const int nb = blockIdx.x;
    const int n0 = nb * 128;

    __shared__ __align__(16) unsigned short As[2][8192];
    __shared__ __align__(16) unsigned short B3s[2][4096];
    __shared__ int rowids[256];
    __shared__ float rowwt[256];

    const int t = threadIdx.x;
    if (t < 256) {
        int idx = m0 + t;
        if (idx < cnt) { rowids[t] = lists[e * N_TOK + idx]; rowwt[t] = wts[e * N_TOK + idx]; }
        else           { rowids[t] = -1; rowwt[t] = 0.f; }
    }

    const int lane = t & 63, wv = t >> 6;
    const int wm = (wv >> 1) * 64, wn = (wv & 1) * 64;
    const int fr = lane & 15, kq = lane >> 4;

    float bb3[4];
#pragma unroll
    for (int ni = 0; ni < 4; ni++)
        bb3[ni] = b3[e * DIM + n0 + wn + ni * 16 + fr];
    __syncthreads();

    const int srow = t & 255;
    const int kqA  = t >> 8;
    const int hb7 = (base[e] + m0) >> 7;
    const unsigned short* HtRow = Hsw + (size_t)(hb7 + (srow >> 7)) * (KS2 * 4096) + (srow & 127) * 8;
    const unsigned short* W3t = W3sw + ((size_t)e * NB2 + nb) * (KS2 * 4096);
    const int lbA0 = (t & ~63) * 8;
    const int lbA1 = (512 + (t & ~63)) * 8;
    const int lbB  = (t & ~63) * 8;

    f32x4 acc[4][4];
    const f32x4 fz = {0.f, 0.f, 0.f, 0.f};
#pragma unroll
    for (int i = 0; i < 4; i++)
#pragma unroll
        for (int j = 0; j < 4; j++) acc[i][j] = fz;

    #define F2_STAGE(buf, ks) do {                                          \
        gl_lds16(HtRow + (ks) * 4096 + kqA * 1024,       &As[buf][lbA0]);   \
        gl_lds16(HtRow + (ks) * 4096 + (kqA + 2) * 1024, &As[buf][lbA1]);   \
        gl_lds16(W3t + (ks) * 4096 + t * 8, &B3s[buf][lbB]);                \
    } while (0)

    #define F2_COMPUTE(buf) do {                                                    \
        short8 af[4];                                                               \
        _Pragma("unroll")                                                           \
        for (int mi = 0; mi < 4; mi++)                                              \
            af[mi] = *(const short8*)&As[buf][(kq * 256 + wm + mi * 16 + fr) * 8];  \
        _Pragma("unroll")                                                           \
        for (int ni = 0; ni < 4; ni++) {                                            \
            short8 bf3 = *(const short8*)&B3s[buf][(kq * 128 + wn + ni * 16 + fr) * 8]; \
            _Pragma("unroll")                                                       \
            for (int mi = 0; mi < 4; mi++)                                          \
                acc[mi][ni] = __builtin_amdgcn_mfma_f32_16x16x32_bf16(af[mi], bf3, acc[mi][ni], 0, 0, 0); \
        }                                                                           \
    } while (0)

    #define VM3  asm volatile("s_waitcnt vmcnt(3)" ::: "memory")

    F2_STAGE(0, 0);
    for (int ks = 0; ks < KS2 - 2; ks += 2) {
        F2_STAGE(1, ks + 1); VM3; BAR; F2_COMPUTE(0); BAR;
        F2_STAGE(0, ks + 2); VM3; BAR; F2_COMPUTE(1); BAR;
    }
    F2_STAGE(1, KS2 - 1); VM3; BAR; F2_COMPUTE(0); BAR;
    VM0; BAR; F2_COMPUTE(1);

#pragma unroll
    for (int ni = 0; ni < 4; ni++) {
        int col = n0 + wn + ni * 16 + fr;
#pragma unroll
        for (int mi = 0; mi < 4; mi++) {
#pragma unroll
            for (int j = 0; j < 4; j++) {
                int rl = wm + mi * 16 + kq * 4 + j;
                int rid = rowids[rl];
                if (rid < 0) continue;
                float v = (acc[mi][ni][j] + bb3[ni]) * rowwt[rl];
                atomicAdd(&out[(size_t)(rid >> 1) * DIM + col], v);
            }
        }
    }
    #undef F2_STAGE
    #undef F2_COMPUTE
}

extern "C" void kernel_launch(void* const* d_in, const int* in_sizes, int n_in,
                              void* d_out, int out_size, void* d_ws, size_t ws_size,
                              hipStream_t stream) {
    (void)in_sizes; (void)n_in; (void)out_size; (void)ws_size;
    const float* x      = (const float*)d_in[0];
    const float* gate_w = (const float*)d_in[1];
    const float* gate_b = (const float*)d_in[2];
    const float* w1     = (const float*)d_in[3];
    const float* b1     = (const float*)d_in[4];
    const float* w2     = (const float*)d_in[5];
    const float* b2     = (const float*)d_in[6];
    const float* w3     = (const float*)d_in[7];
    const float* b3     = (const float*)d_in[8];
    float* out = (float*)d_out;

    char* ws = (char*)d_ws;
    float* usage  = (float*)ws;                                   // @0, 32 B
    int*   counts = (int*)(ws + 32);                              // @32, 32 B
    int*   base   = (int*)(ws + 64);                              // @64, 64 B
    int*   lists  = (int*)(ws + 128);                             // 256 KB
    float* wts    = (float*)(ws + 128 + (size_t)NE * N_TOK * 4);  // 256 KB
    unsigned short* Hsw  = (unsigned short*)(ws + (1ull  << 20)); // @1 MiB, 69 MiB region
    unsigned short* W1sw = (unsigned short*)(ws + (70ull << 20)); // @70 MiB, 32 MiB
    unsigned short* W2sw = (unsigned short*)(ws + (102ull << 20));// @102 MiB, 32 MiB
    unsigned short* W3sw = W1sw;                                  // reused after ffn1
    unsigned short* Xbf  = (unsigned short*)d_out;                // lives in d_out pre-zeroing

    hipMemsetAsync(ws, 0, 128, stream);

    gate_kernel<<<N_TOK / 4, 256, 0, stream>>>(x, gate_w, gate_b, usage, counts, lists, wts);
    prefix_kernel<<<1, 64, 0, stream>>>(counts, base);
    xconv_kernel<<<N_TOK * DIM / (256 * 8), 256, 0, stream>>>(x, Xbf);

    dim3 gW1(KS1, NB1, NE);                 // w1,w2: K=DIM, N=HID
    wswz_kernel<<<gW1, 256, 0, stream>>>(w1, W1sw, DIM, HID);
    wswz_kernel<<<gW1, 256, 0, stream>>>(w2, W2sw, DIM, HID);

    dim3 gA(NB1, N_TOK * 2 / 256, NE);
    ffn1_mfma_kernel<<<gA, 512, 0, stream>>>(Xbf, W1sw, W2sw, b1, b2, counts, lists, base, Hsw);

    hipMemsetAsync(d_out, 0, (size_t)N_TOK * DIM * sizeof(float), stream);
    loss_kernel<<<1, 64, 0, stream>>>(usage, out + (size_t)N_TOK * DIM);

    dim3 gW3(KS2, NB2, NE);                 // w3: K=HID, N=DIM
    wswz_kernel<<<gW3, 256, 0, stream>>>(w3, W3sw, HID, DIM);

    dim3 gB(NB2, N_TOK * 2 / 256, NE);
    ffn2_mfma_kernel<<<gB, 512, 0, stream>>>(Hsw, W3sw, b3, counts, lists, wts, base, out);
}

// Round 8
// 696.539 us; speedup vs baseline: 1.2695x; 1.0101x over previous
//
#include <hip/hip_runtime.h>
#include <hip/hip_bf16.h>
#include <math.h>

#define N_TOK 8192
#define DIM   1024
#define HID   2048
#define NE    8
#define NT1   16     // DIM/64 K-tiles (ffn1)
#define NT2   32     // HID/64 K-tiles (ffn2)
#define NB1   16     // HID/128 panels (ffn1)
#define NB2   4      // DIM/256 panels (ffn2)
#define PANEL1_SH ((size_t)DIM * 128)   // shorts per 128-col ffn1 weight panel
#define PANEL3_SH ((size_t)HID * 128)   // shorts per 128-col w3 panel
#define HBLK_SH   ((size_t)HID * 128)   // shorts per 128-row Hsw block

typedef __attribute__((ext_vector_type(8))) short short8;
typedef __attribute__((ext_vector_type(4))) float f32x4;

__device__ __forceinline__ unsigned short f2bf(float f) {
    unsigned int u = __builtin_bit_cast(unsigned int, f);
    unsigned int r = (u + 0x7fffu + ((u >> 16) & 1u)) >> 16;   // RNE
    return (unsigned short)r;
}

// async global -> LDS, 16B/lane; LDS dest = wave-uniform base + lane*16 (HW)
__device__ __forceinline__ void gl_lds16(const unsigned short* g, unsigned short* l) {
    __builtin_amdgcn_global_load_lds(
        (const __attribute__((address_space(1))) void*)g,
        (__attribute__((address_space(3))) void*)l, 16, 0, 0);
}

#define VM4  asm volatile("s_waitcnt vmcnt(4)" ::: "memory")
#define VM0  asm volatile("s_waitcnt vmcnt(0)" ::: "memory")
#define BAR  __builtin_amdgcn_s_barrier()

// ---------------- gating (+ fused x->bf16 conversion) ----------------
__global__ __launch_bounds__(256) void gate_kernel(
    const float* __restrict__ x, const float* __restrict__ gw, const float* __restrict__ gb,
    float* __restrict__ usage, int* __restrict__ counts,
    int* __restrict__ lists, float* __restrict__ wts,
    unsigned short* __restrict__ xb)
{
    const int wave_in_block = threadIdx.x >> 6;
    const int lane = threadIdx.x & 63;
    const int tok = blockIdx.x * 4 + wave_in_block;

    __shared__ float su[NE];
    if (threadIdx.x < NE) su[threadIdx.x] = 0.f;
    __syncthreads();

    float acc[NE];
#pragma unroll
    for (int e = 0; e < NE; e++) acc[e] = 0.f;

    const float* xr = x + (size_t)tok * DIM;
    unsigned short* xbr = xb + (size_t)tok * DIM;
    for (int d = lane; d < DIM; d += 64) {
        float xv = xr[d];
        xbr[d] = f2bf(xv);                       // fused conversion (x read once)
        const float4* g4 = (const float4*)(gw + (size_t)d * NE);
        float4 ga = g4[0], gc = g4[1];
        acc[0] = fmaf(xv, ga.x, acc[0]);
        acc[1] = fmaf(xv, ga.y, acc[1]);
        acc[2] = fmaf(xv, ga.z, acc[2]);
        acc[3] = fmaf(xv, ga.w, acc[3]);
        acc[4] = fmaf(xv, gc.x, acc[4]);
        acc[5] = fmaf(xv, gc.y, acc[5]);
        acc[6] = fmaf(xv, gc.z, acc[6]);
        acc[7] = fmaf(xv, gc.w, acc[7]);
    }
#pragma unroll
    for (int e = 0; e < NE; e++) {
#pragma unroll
        for (int off = 32; off > 0; off >>= 1)
            acc[e] += __shfl_xor(acc[e], off);
    }

    if (lane == 0) {
        float lg[NE], p[NE];
        float mx = -1e30f;
#pragma unroll
        for (int e = 0; e < NE; e++) { lg[e] = acc[e] + gb[e]; mx = fmaxf(mx, lg[e]); }
        float s = 0.f;
#pragma unroll
        for (int e = 0; e < NE; e++) { p[e] = __expf(lg[e] - mx); s += p[e]; }
        float inv = 1.f / s;
#pragma unroll
        for (int e = 0; e < NE; e++) p[e] *= inv;

#pragma unroll
        for (int e = 0; e < NE; e++) atomicAdd(&su[e], p[e]);

        int e1 = 0; float v1 = p[0];
#pragma unroll
        for (int e = 1; e < NE; e++) if (p[e] > v1) { v1 = p[e]; e1 = e; }
        int e2 = -1; float v2 = -1e30f;
#pragma unroll
        for (int e = 0; e < NE; e++) if (e != e1 && p[e] > v2) { v2 = p[e]; e2 = e; }

        int pos1 = atomicAdd(&counts[e1], 1);
        lists[e1 * N_TOK + pos1] = tok * 2 + 0;
        wts[e1 * N_TOK + pos1] = v1;
        int pos2 = atomicAdd(&counts[e2], 1);
        lists[e2 * N_TOK + pos2] = tok * 2 + 1;
        wts[e2 * N_TOK + pos2] = v2;
    }
    __syncthreads();
    if (threadIdx.x < NE) atomicAdd(&usage[threadIdx.x], su[threadIdx.x]);
}

__global__ void loss_kernel(const float* __restrict__ usage, float* __restrict__ out_loss)
{
    if (threadIdx.x == 0) {
        float l = 0.f;
        for (int e = 0; e < NE; e++) {
            float u = usage[e] / (float)N_TOK;
            l += u * logf(u + 1e-9f);
        }
        *out_loss = l;
    }
}

__global__ void prefix_kernel(const int* __restrict__ counts, int* __restrict__ base)
{
    if (threadIdx.x == 0) {
        int b = 0;
        for (int e = 0; e < NE; e++) { base[e] = b; b += (counts[e] + 127) & ~127; }
    }
}

// ---------------- W (f32 [K][N]) -> bf16 panels [e][np128][kq_g=K/8][row128][8] ----------------
__global__ __launch_bounds__(256) void wswz_kernel(
    const float* __restrict__ in, unsigned short* __restrict__ out, int K, int N)
{
    const int e  = blockIdx.z;
    const int np = blockIdx.y;
    const int ks = blockIdx.x;            // 32-k group
    const float* in_e = in + (size_t)e * K * N;
    unsigned short* out_p = out + ((size_t)e * (N >> 7) + np) * ((size_t)K * 128)
                                + (size_t)ks * 4 * 1024;
    const int t = threadIdx.x;
#pragma unroll
    for (int it = 0; it < 2; it++) {
        int idx = it * 256 + t;           // 0..511
        int row = idx & 127, kql = idx >> 7;
        const float* src = in_e + (size_t)((ks * 4 + kql) * 8) * N + np * 128 + row;
        short8 v;
#pragma unroll
        for (int s = 0; s < 8; s++) v[s] = (short)f2bf(src[(size_t)s * N]);
        *(short8*)(out_p + (size_t)(kql * 128 + row) * 8) = v;
    }
}

// combined w1+w2 swizzle (one launch)
__global__ __launch_bounds__(256) void wswz12_kernel(
    const float* __restrict__ w1, const float* __restrict__ w2,
    unsigned short* __restrict__ o1, unsigned short* __restrict__ o2)
{
    const int which = blockIdx.z & 1;
    const int e  = blockIdx.z >> 1;
    const int np = blockIdx.y;
    const int ks = blockIdx.x;
    const float* in_e = (which ? w2 : w1) + (size_t)e * DIM * HID;
    unsigned short* out_p = (which ? o2 : o1)
        + ((size_t)e * NB1 + np) * PANEL1_SH + (size_t)ks * 4 * 1024;
    const int t = threadIdx.x;
#pragma unroll
    for (int it = 0; it < 2; it++) {
        int idx = it * 256 + t;
        int row = idx & 127, kql = idx >> 7;
        const float* src = in_e + (size_t)((ks * 4 + kql) * 8) * HID + np * 128 + row;
        short8 v;
#pragma unroll
        for (int s = 0; s < 8; s++) v[s] = (short)f2bf(src[(size_t)s * HID]);
        *(short8*)(out_p + (size_t)(kql * 128 + row) * 8) = v;
    }
}

#define CLUSTER(ACC, BF)                                                             \
    __builtin_amdgcn_s_setprio(1);                                                   \
    _Pragma("unroll")                                                                \
    for (int ni = 0; ni < 4; ni++) {                                                 \
        _Pragma("unroll")                                                            \
        for (int mi = 0; mi < 4; mi++)                                               \
            ACC[mi][ni] = __builtin_amdgcn_mfma_f32_16x16x32_bf16(af[mi], BF[ni],    \
                                                                  ACC[mi][ni], 0, 0, 0); \
    }                                                                                \
    __builtin_amdgcn_s_setprio(0)

#define AF_IDX(H, mi)  ((((H)*4 + kc)*256 + (wm + (mi)*16 + fr))*8)
#define BF_IDX(H, ni)  ((((H)*4 + kc)*128 + (wn + (ni)*16 + fr))*8)

// ---------------- pass A: Xg @ {w1,w2} -> swiglu -> Hsw ----------------
// BM=256, dual BN=128; BK=64; 512 thr (8 waves, 4M x 2N, wave 64x64 dual-acc);
// 4-phase counted-vmcnt pipeline, 1 block/CU (128KB LDS).
__global__ __launch_bounds__(512, 2) void ffn1_mfma_kernel(
    const unsigned short* __restrict__ Xbf,
    const unsigned short* __restrict__ W1sw, const unsigned short* __restrict__ W2sw,
    const float* __restrict__ b1, const float* __restrict__ b2,
    const int* __restrict__ counts, const int* __restrict__ lists, const int* __restrict__ base,
    unsigned short* __restrict__ Hsw)
{
    const int e = blockIdx.z;
    const int cnt = counts[e];
    const int m0 = blockIdx.y * 256;
    if (m0 >= cnt) return;
    const int nbx = blockIdx.x;

    __shared__ __align__(16) unsigned short As[2][16384];   // 2 x 32 KB
    __shared__ __align__(16) unsigned short B1s[2][8192];   // 2 x 16 KB
    __shared__ __align__(16) unsigned short B2s[2][8192];
    __shared__ int rowids[256];

    const int t = threadIdx.x;
    if (t < 256) rowids[t] = (m0 + t < cnt) ? lists[e * N_TOK + m0 + t] : -1;

    const int lane = t & 63, wv = t >> 6;
    const int wm = (wv >> 1) * 64;      // 4 M-waves
    const int wn = (wv & 1) * 64;       // 2 N-waves
    const int fr = lane & 15, kc = lane >> 4;

    float bb1[4], bb2[4];
#pragma unroll
    for (int ni = 0; ni < 4; ni++) {
        int col = nbx * 128 + wn + ni * 16 + fr;
        bb1[ni] = b1[e * HID + col];
        bb2[ni] = b2[e * HID + col];
    }
    __syncthreads();   // rowids visible; all prior VMEM drained

    const int srow = t & 255;
    const int rid_s = rowids[srow];
    const unsigned short* Ap  = Xbf + (size_t)(rid_s < 0 ? 0 : (rid_s >> 1)) * DIM;
    const unsigned short* W1t = W1sw + ((size_t)e * NB1 + nbx) * PANEL1_SH;
    const unsigned short* W2t = W2sw + ((size_t)e * NB1 + nbx) * PANEL1_SH;
    const int i2 = t >> 8;              // 0/1
    const int lu = t & ~63;             // wave-uniform lane base

    f32x4 acc1[4][4], acc2[4][4];
    const f32x4 fz = {0.f, 0.f, 0.f, 0.f};
#pragma unroll
    for (int i = 0; i < 4; i++)
#pragma unroll
        for (int j = 0; j < 4; j++) { acc1[i][j] = fz; acc2[i][j] = fz; }

    // stage one 32-k half: A(2) + B1(1) + B2(1) = 4 VMEM instr per thread
    #define F1_STAGE_H(buf, tile, H) do {                                            \
        const int koff = (tile) * 64 + (H) * 32;                                     \
        gl_lds16(Ap + koff + i2 * 8,       &As[buf][((H)*1024 +       lu) * 8]);     \
        gl_lds16(Ap + koff + (2+i2) * 8,   &As[buf][((H)*1024 + 512 + lu) * 8]);     \
        gl_lds16(W1t + ((size_t)(tile)*1024 + (H)*512 + t) * 8,                      \
                 &B1s[buf][((H)*512 + lu) * 8]);                                     \
        gl_lds16(W2t + ((size_t)(tile)*1024 + (H)*512 + t) * 8,                      \
                 &B2s[buf][((H)*512 + lu) * 8]);                                     \
    } while (0)

    F1_STAGE_H(0, 0, 0);
    F1_STAGE_H(0, 0, 1);
    VM4; BAR;                            // H0 of tile 0 ready

    short8 af[4], bfr[4];
    for (int tl = 0; tl < NT1; ++tl) {
        const int bf = tl & 1, nbf = bf ^ 1;
        const bool more = (tl + 1 < NT1);
        // P0: H0 x acc1
#pragma unroll
        for (int mi = 0; mi < 4; mi++) af[mi] = *(const short8*)&As[bf][AF_IDX(0, mi)];
#pragma unroll
        for (int ni = 0; ni < 4; ni++) bfr[ni] = *(const short8*)&B1s[bf][BF_IDX(0, ni)];
        if (more) F1_STAGE_H(nbf, tl + 1, 0);
        BAR;
        CLUSTER(acc1, bfr);
        BAR;
        // P1: H0 x acc2  (+ wait for this tile's H1)
#pragma unroll
        for (int ni = 0; ni < 4; ni++) bfr[ni] = *(const short8*)&B2s[bf][BF_IDX(0, ni)];
        if (more) { VM4; } else { VM0; }
        BAR;
        CLUSTER(acc2, bfr);
        BAR;
        // P2: H1 x acc1
#pragma unroll
        for (int mi = 0; mi < 4; mi++) af[mi] = *(const short8*)&As[bf][AF_IDX(1, mi)];
#pragma unroll
        for (int ni = 0; ni < 4; ni++) bfr[ni] = *(const short8*)&B1s[bf][BF_IDX(1, ni)];
        if (more) F1_STAGE_H(nbf, tl + 1, 1);
        BAR;
        CLUSTER(acc1, bfr);
        BAR;
        // P3: H1 x acc2  (+ wait for next tile's H0)
#pragma unroll
        for (int ni = 0; ni < 4; ni++) bfr[ni] = *(const short8*)&B2s[bf][BF_IDX(1, ni)];
        if (more) { VM4; }
        BAR;
        CLUSTER(acc2, bfr);
        BAR;
    }
    #undef F1_STAGE_H

    // epilogue: bias + swiglu -> Hsw (128-row-block tiled layout)
    const int hb7 = (base[e] + m0) >> 7;
#pragma unroll
    for (int ni = 0; ni < 4; ni++) {
        int col = nbx * 128 + wn + ni * 16 + fr;
        size_t cbase = (size_t)(col >> 3) * 1024 + (col & 7);
#pragma unroll
        for (int mi = 0; mi < 4; mi++) {
#pragma unroll
            for (int j = 0; j < 4; j++) {
                int rl = wm + mi * 16 + kc * 4 + j;
                if (rowids[rl] < 0) continue;
                float v1 = acc1[mi][ni][j] + bb1[ni];
                float v2 = acc2[mi][ni][j] + bb2[ni];
                float h = v1 * (1.f / (1.f + __expf(-v2)));
                Hsw[(size_t)(hb7 + (rl >> 7)) * HBLK_SH + cbase + (size_t)(rl & 127) * 8] = f2bf(h);
            }
        }
    }
}

// ---------------- pass B: Hsw @ w3 + b3, scale, atomicAdd into out ----------------
// BM=256, BN=256 (two 128-col halves as dual acc); same 4-phase pipeline.
__global__ __launch_bounds__(512, 2) void ffn2_mfma_kernel(
    const unsigned short* __restrict__ Hsw,
    const unsigned short* __restrict__ W3sw, const float* __restrict__ b3,
    const int* __restrict__ counts, const int* __restrict__ lists, const float* __restrict__ wts,
    const int* __restrict__ base,
    float* __restrict__ out)
{
    const int e = blockIdx.z;
    const int cnt = counts[e];
    const int m0 = blockIdx.y * 256;
    if (m0 >= cnt) return;
    const int nbx = blockIdx.x;

    __shared__ __align__(16) unsigned short As[2][16384];
    __shared__ __align__(16) unsigned short B1s[2][8192];
    __shared__ __align__(16) unsigned short B2s[2][8192];
    __shared__ int rowids[256];
    __shared__ float rowwt[256];

    const int t = threadIdx.x;
    if (t < 256) {
        int idx = m0 + t;
        if (idx < cnt) { rowids[t] = lists[e * N_TOK + idx]; rowwt[t] = wts[e * N_TOK + idx]; }
        else           { rowids[t] = -1; rowwt[t] = 0.f; }
    }

    const int lane = t & 63, wv = t >> 6;
    const int wm = (wv >> 1) * 64;
    const int wn = (wv & 1) * 64;
    const int fr = lane & 15, kc = lane >> 4;

    float bb3a[4], bb3b[4];
#pragma unroll
    for (int ni = 0; ni < 4; ni++) {
        int col = nbx * 256 + wn + ni * 16 + fr;
        bb3a[ni] = b3[e * DIM + col];
        bb3b[ni] = b3[e * DIM + col + 128];
    }
    __syncthreads();

    const int srow = t & 255;
    const int hb7 = (base[e] + m0) >> 7;
    const unsigned short* HtA = Hsw + (size_t)(hb7 + (srow >> 7)) * HBLK_SH + (size_t)(srow & 127) * 8;
    const unsigned short* W3a = W3sw + ((size_t)e * NB2 * 2 + nbx * 2)     * PANEL3_SH;
    const unsigned short* W3b = W3sw + ((size_t)e * NB2 * 2 + nbx * 2 + 1) * PANEL3_SH;
    const int i2 = t >> 8;
    const int lu = t & ~63;

    f32x4 acc1[4][4], acc2[4][4];
    const f32x4 fz = {0.f, 0.f, 0.f, 0.f};
#pragma unroll
    for (int i = 0; i < 4; i++)
#pragma unroll
        for (int j = 0; j < 4; j++) { acc1[i][j] = fz; acc2[i][j] = fz; }

    #define F2_STAGE_H(buf, tile, H) do {                                            \
        gl_lds16(HtA + (size_t)((tile)*8 + (H)*4 +     i2) * 1024,                   \
                 &As[buf][((H)*1024 +       lu) * 8]);                               \
        gl_lds16(HtA + (size_t)((tile)*8 + (H)*4 + 2 + i2) * 1024,                   \
                 &As[buf][((H)*1024 + 512 + lu) * 8]);                               \
        gl_lds16(W3a + ((size_t)(tile)*1024 + (H)*512 + t) * 8,                      \
                 &B1s[buf][((H)*512 + lu) * 8]);                                     \
        gl_lds16(W3b + ((size_t)(tile)*1024 + (H)*512 + t) * 8,                      \
                 &B2s[buf][((H)*512 + lu) * 8]);                                     \
    } while (0)

    F2_STAGE_H(0, 0, 0);
    F2_STAGE_H(0, 0, 1);
    VM4; BAR;

    short8 af[4], bfr[4];
    for (int tl = 0; tl < NT2; ++tl) {
        const int bf = tl & 1, nbf = bf ^ 1;
        const bool more = (tl + 1 < NT2);
#pragma unroll
        for (int mi = 0; mi < 4; mi++) af[mi] = *(const short8*)&As[bf][AF_IDX(0, mi)];
#pragma unroll
        for (int ni = 0; ni < 4; ni++) bfr[ni] = *(const short8*)&B1s[bf][BF_IDX(0, ni)];
        if (more) F2_STAGE_H(nbf, tl + 1, 0);
        BAR;
        CLUSTER(acc1, bfr);
        BAR;
#pragma unroll
        for (int ni = 0; ni < 4; ni++) bfr[ni] = *(const short8*)&B2s[bf][BF_IDX(0, ni)];
        if (more) { VM4; } else { VM0; }
        BAR;
        CLUSTER(acc2, bfr);
        BAR;
#pragma unroll
        for (int mi = 0; mi < 4; mi++) af[mi] = *(const short8*)&As[bf][AF_IDX(1, mi)];
#pragma unroll
        for (int ni = 0; ni < 4; ni++) bfr[ni] = *(const short8*)&B1s[bf][BF_IDX(1, ni)];
        if (more) F2_STAGE_H(nbf, tl + 1, 1);
        BAR;
        CLUSTER(acc1, bfr);
        BAR;
#pragma unroll
        for (int ni = 0; ni < 4; ni++) bfr[ni] = *(const short8*)&B2s[bf][BF_IDX(1, ni)];
        if (more) { VM4; }
        BAR;
        CLUSTER(acc2, bfr);
        BAR;
    }
    #undef F2_STAGE_H

#pragma unroll
    for (int ni = 0; ni < 4; ni++) {
        int colA = nbx * 256 + wn + ni * 16 + fr;
#pragma unroll
        for (int mi = 0; mi < 4; mi++) {
#pragma unroll
            for (int j = 0; j < 4; j++) {
                int rl = wm + mi * 16 + kc * 4 + j;
                int rid = rowids[rl];
                if (rid < 0) continue;
                float w = rowwt[rl];
                float* orow = out + (size_t)(rid >> 1) * DIM;
                atomicAdd(&orow[colA],       (acc1[mi][ni][j] + bb3a[ni]) * w);
                atomicAdd(&orow[colA + 128], (acc2[mi][ni][j] + bb3b[ni]) * w);
            }
        }
    }
}

extern "C" void kernel_launch(void* const* d_in, const int* in_sizes, int n_in,
                              void* d_out, int out_size, void* d_ws, size_t ws_size,
                              hipStream_t stream) {
    (void)in_sizes; (void)n_in; (void)out_size; (void)ws_size;
    const float* x      = (const float*)d_in[0];
    const float* gate_w = (const float*)d_in[1];
    const float* gate_b = (const float*)d_in[2];
    const float* w1     = (const float*)d_in[3];
    const float* b1     = (const float*)d_in[4];
    const float* w2     = (const float*)d_in[5];
    const float* b2     = (const float*)d_in[6];
    const float* w3     = (const float*)d_in[7];
    const float* b3     = (const float*)d_in[8];
    float* out = (float*)d_out;

    char* ws = (char*)d_ws;
    float* usage  = (float*)ws;                                   // @0, 32 B
    int*   counts = (int*)(ws + 32);                              // @32, 32 B
    int*   base   = (int*)(ws + 64);                              // @64, 64 B
    int*   lists  = (int*)(ws + 128);                             // 256 KB
    float* wts    = (float*)(ws + 128 + (size_t)NE * N_TOK * 4);  // 256 KB
    unsigned short* Hsw  = (unsigned short*)(ws + (1ull  << 20)); // @1 MiB, 68 MiB
    unsigned short* W1sw = (unsigned short*)(ws + (70ull << 20)); // @70 MiB, 32 MiB
    unsigned short* W2sw = (unsigned short*)(ws + (102ull << 20));// @102 MiB, 32 MiB
    unsigned short* W3sw = W1sw;                                  // reused after ffn1
    unsigned short* Xbf  = (unsigned short*)d_out;                // lives in d_out pre-zeroing

    hipMemsetAsync(ws, 0, 128, stream);

    gate_kernel<<<N_TOK / 4, 256, 0, stream>>>(x, gate_w, gate_b, usage, counts, lists, wts, Xbf);
    prefix_kernel<<<1, 64, 0, stream>>>(counts, base);

    dim3 gW12(DIM / 32, NB1, NE * 2);
    wswz12_kernel<<<gW12, 256, 0, stream>>>(w1, w2, W1sw, W2sw);

    dim3 gA(NB1, 64, NE);
    ffn1_mfma_kernel<<<gA, 512, 0, stream>>>(Xbf, W1sw, W2sw, b1, b2, counts, lists, base, Hsw);

    hipMemsetAsync(d_out, 0, (size_t)N_TOK * DIM * sizeof(float), stream);
    loss_kernel<<<1, 64, 0, stream>>>(usage, out + (size_t)N_TOK * DIM);

    dim3 gW3(HID / 32, DIM / 128, NE);
    wswz_kernel<<<gW3, 256, 0, stream>>>(w3, W3sw, HID, DIM);

    dim3 gB(NB2, 64, NE);
    ffn2_mfma_kernel<<<gB, 512, 0, stream>>>(Hsw, W3sw, b3, counts, lists, wts, base, out);
}